// Round 5
// baseline (160.974 us; speedup 1.0000x reference)
//
#include <hip/hip_runtime.h>
#include <hip/hip_bf16.h>
#include <cstdint>

#define EMBED   1024
#define NHEADS  16
#define HDIM    64
#define SEQ     2048
#define BSZ     2
#define MTOT    (BSZ*SEQ)   // 4096
#define NCLS    1000
#define NPAD    1024

typedef __attribute__((ext_vector_type(8))) short short8;
typedef __attribute__((ext_vector_type(4))) short short4v;
typedef __attribute__((ext_vector_type(4))) float float4v;

typedef __attribute__((address_space(3))) unsigned lds_uint;
typedef __attribute__((address_space(1))) const unsigned gbl_uint;

__device__ __forceinline__ void gl2lds16(const void* g, void* l) {
    __builtin_amdgcn_global_load_lds((gbl_uint*)g, (lds_uint*)l, 16, 0, 0);
}

#define WAITVM16() asm volatile("s_waitcnt vmcnt(16)" ::: "memory")
#define WAITVM8()  asm volatile("s_waitcnt vmcnt(8)" ::: "memory")
#define WAITVM0()  asm volatile("s_waitcnt vmcnt(0)" ::: "memory")
#define BAR()      asm volatile("s_barrier" ::: "memory")

__device__ __forceinline__ void storeC(float* p, float v) { *p = v; }
__device__ __forceinline__ void storeC(__hip_bfloat16* p, float v) { *p = __float2bfloat16(v); }

// ---------------------------------------------------------------------------
// Convert fp32 x, W_in to bf16 ws copies; zero G. (W_out handled in weff.)
// ---------------------------------------------------------------------------
#define XN4  ((MTOT*EMBED)/4)    // 1,048,576
#define WN4  ((EMBED*EMBED)/4)   // 262,144
#define GN4  (32*64*64/4)        // 32,768
__global__ __launch_bounds__(256)
void conv_inputs(const float* __restrict__ x, const float* __restrict__ Win,
                 __hip_bfloat16* __restrict__ xb, __hip_bfloat16* __restrict__ Winb,
                 float* __restrict__ G) {
    const long i4 = (long)blockIdx.x * 256 + threadIdx.x;  // float4 index
    if (i4 < GN4)
        *(float4v*)(G + i4 * 4) = (float4v){0.f, 0.f, 0.f, 0.f};
    float4v v;
    __hip_bfloat16* dst;
    if (i4 < XN4) {
        v = *(const float4v*)(x + i4 * 4);
        dst = xb + i4 * 4;
    } else {
        const long j = i4 - XN4;
        v = *(const float4v*)(Win + j * 4);
        dst = Winb + j * 4;
    }
    short4v o;
#pragma unroll
    for (int u = 0; u < 4; u++)
        ((__hip_bfloat16*)&o)[u] = __float2bfloat16(v[u]);
    *(short4v*)dst = o;
}

// ---------------------------------------------------------------------------
// GEMM: C[m][n] = sum_k A[m][k]*B[n][k] + bias[n]  (row-major, B^T input)
// 128x128 tile, BK=64, XOR-swizzled LDS, 3-STAGE pipeline: prefetch distance
// 2 iters (~700 cyc of compute) covers global-load latency; s_waitcnt
// vmcnt(16) waits only the current tile's 8 loads, the other 16 stay in
// flight across the barrier. 96 KiB LDS, 1 block/CU.
// ---------------------------------------------------------------------------
template <typename CT>
__global__ __launch_bounds__(256)
void gemm_bt_bias(const __hip_bfloat16* __restrict__ A,
                  const __hip_bfloat16* __restrict__ B,
                  const float* __restrict__ bias,
                  CT* __restrict__ C,
                  int K, int nstore, int cstride, long bstride) {
    __shared__ __hip_bfloat16 As[3][128 * 64];   // 3 x 16 KiB, swizzled
    __shared__ __hip_bfloat16 Bs[3][128 * 64];

    const int t    = threadIdx.x;
    const int bm   = blockIdx.x * 128;
    const int bn   = blockIdx.y * 128;
    const __hip_bfloat16* Bb = B + (long)(bm >> 11) * bstride;
    const int wave = t >> 6, lane = t & 63;
    const int wm   = (wave & 1) * 64, wn = (wave >> 1) * 64;
    const int lrow = lane & 15, lq = lane >> 4;

    // staging map: chunk ci = i*256+t; LDS slot ci holds global
    // (row = ci>>3, k-chunk = (ci&7)^(row&7))  [16B chunks, 8 per 64-k row]
    const __hip_bfloat16* Arow[4];
    const __hip_bfloat16* Brow[4];
#pragma unroll
    for (int i = 0; i < 4; i++) {
        const int ci = i * 256 + t;
        const int r  = ci >> 3;
        const int sc = ((ci & 7) ^ (r & 7)) * 8;
        Arow[i] = A  + (long)(bm + r) * K + sc;
        Brow[i] = Bb + (long)(bn + r) * K + sc;
    }

    float4v acc[4][4];
#pragma unroll
    for (int i = 0; i < 4; i++)
#pragma unroll
        for (int j = 0; j < 4; j++) acc[i][j] = (float4v){0.f, 0.f, 0.f, 0.f};

    const int nIter = K >> 6;   // >= 3 (K = 1024 here)

#define STAGE_TILE(k0, Ad, Bd)                                                  \
    do {                                                                        \
        _Pragma("unroll")                                                       \
        for (int i = 0; i < 4; i++)                                             \
            gl2lds16(Arow[i] + (k0), (char*)(Ad) + (i * 256 + t) * 16);         \
        _Pragma("unroll")                                                       \
        for (int i = 0; i < 4; i++)                                             \
            gl2lds16(Brow[i] + (k0), (char*)(Bd) + (i * 256 + t) * 16);         \
    } while (0)

    STAGE_TILE(0,  As[0], Bs[0]);
    STAGE_TILE(64, As[1], Bs[1]);

    int cur = 0;
    for (int it = 0; it < nIter; ++it) {
        if (it + 2 < nIter) {
            const int pf = (cur == 0) ? 2 : cur - 1;   // (cur+2)%3
            STAGE_TILE((it + 2) << 6, As[pf], Bs[pf]);
            WAITVM16();      // tile `it` landed; 16 prefetch loads in flight
        } else if (it + 1 < nIter) {
            WAITVM8();
        } else {
            WAITVM0();
        }
        BAR();               // tile `it` staged for all waves

        const __hip_bfloat16* Ac = As[cur];
        const __hip_bfloat16* Bc = Bs[cur];
#pragma unroll
        for (int kk = 0; kk < 2; kk++) {
            short8 af[4], bf[4];
#pragma unroll
            for (int i = 0; i < 4; i++) {
                const int row = wm + i * 16 + lrow;
                const int sc  = (kk * 4 + lq) ^ (row & 7);
                af[i] = *(const short8*)(Ac + row * 64 + sc * 8);
            }
#pragma unroll
            for (int j = 0; j < 4; j++) {
                const int row = wn + j * 16 + lrow;
                const int sc  = (kk * 4 + lq) ^ (row & 7);
                bf[j] = *(const short8*)(Bc + row * 64 + sc * 8);
            }
#pragma unroll
            for (int i = 0; i < 4; i++)
#pragma unroll
                for (int j = 0; j < 4; j++)
                    acc[i][j] = __builtin_amdgcn_mfma_f32_16x16x32_bf16(af[i], bf[j], acc[i][j], 0, 0, 0);
        }
        BAR();               // all waves done reading `cur` before overwrite
        cur = (cur == 2) ? 0 : cur + 1;
    }
#undef STAGE_TILE

    // epilogue: C/D layout col=lane&15, row=lq*4+reg
    float bv[4];
#pragma unroll
    for (int j = 0; j < 4; j++) {
        const int gn = bn + wn + j * 16 + lrow;
        bv[j] = (gn < nstore) ? bias[gn] : 0.f;
    }
#pragma unroll
    for (int i = 0; i < 4; i++) {
        const int gm0 = bm + wm + i * 16 + lq * 4;
#pragma unroll
        for (int j = 0; j < 4; j++) {
            const int gn = bn + wn + j * 16 + lrow;
            if (gn < nstore) {
#pragma unroll
                for (int r = 0; r < 4; r++)
                    storeC(&C[(long)(gm0 + r) * cstride + gn], acc[i][j][r] + bv[j]);
            }
        }
    }
}

// ---------------------------------------------------------------------------
// Gram: G[bh][d1][d2] += sum over 128 rows of P[s][d1]*P[s][d2]  (fp32 atomics)
// Pl stride 68 floats: float4 stores/loads stay 16B-aligned AND banks spread
// over all 32 (write banks 4(r+2s)+u -> conflict-free vs old 16-way).
// ---------------------------------------------------------------------------
__global__ __launch_bounds__(256)
void gram_kernel(const __hip_bfloat16* __restrict__ P, float* __restrict__ G) {
    const int bh = blockIdx.x;       // 0..31
    const int ck = blockIdx.y;       // 0..15
    const int b = bh >> 4, h = bh & 15;
    const int row0 = b * SEQ + ck * 128;

    __shared__ float Pl[128][68];
    const int t = threadIdx.x;
#pragma unroll
    for (int it = 0; it < 4; it++) {
        const int ci = it * 256 + t;
        const int r = ci >> 3, c8 = (ci & 7) * 8;
        short8 v = *(const short8*)(P + (long)(row0 + r) * EMBED + h * HDIM + c8);
        float4v f0, f1;
#pragma unroll
        for (int u = 0; u < 4; u++) {
            f0[u] = __bfloat162float(((const __hip_bfloat16*)&v)[u]);
            f1[u] = __bfloat162float(((const __hip_bfloat16*)&v)[u + 4]);
        }
        *(float4v*)&Pl[r][c8]     = f0;
        *(float4v*)&Pl[r][c8 + 4] = f1;
    }
    __syncthreads();

    const int ty = t >> 4, tx = t & 15;
    float acc[4][4] = {};
    for (int k = 0; k < 128; k++) {
        float4v a  = *(const float4v*)&Pl[k][4 * ty];
        float4v bb = *(const float4v*)&Pl[k][4 * tx];
#pragma unroll
        for (int i = 0; i < 4; i++)
#pragma unroll
            for (int j = 0; j < 4; j++) acc[i][j] += a[i] * bb[j];
    }
    float* Gh = G + bh * 4096;
#pragma unroll
    for (int i = 0; i < 4; i++)
#pragma unroll
        for (int j = 0; j < 4; j++)
            atomicAdd(&Gh[(4 * ty + i) * 64 + 4 * tx + j], acc[i][j]);
}

// ---------------------------------------------------------------------------
// Weff: WeffT[b][n][64h+d1] = scale * sum_d Wout[n][64h+d] * G[b,h][d][d1]
// (G symmetric). Reads W_out fp32 directly (rows >= NCLS zeroed).
// GEMM2 computes out = P @ WeffT^T + b_out.
// ---------------------------------------------------------------------------
__global__ __launch_bounds__(256)
void weff_kernel(const float* __restrict__ Wout, const float* __restrict__ G,
                 __hip_bfloat16* __restrict__ WeffT) {
    const int n0 = blockIdx.x * 64;
    const int h  = blockIdx.y;
    const int b  = blockIdx.z;
    const float* Gh = G + (b * 16 + h) * 4096;

    __shared__ float Wl[64][65];
    __shared__ float Gl[64][64];
    const int t = threadIdx.x;

#pragma unroll
    for (int it = 0; it < 4; it++) {           // Wout slice 64x64 fp32
        const int ci = it * 256 + t;
        const int r = ci >> 4, c4 = (ci & 15) * 4;
        const int gr = n0 + r;
        float4v v = (float4v){0.f, 0.f, 0.f, 0.f};
        if (gr < NCLS)
            v = *(const float4v*)(Wout + (long)gr * EMBED + h * HDIM + c4);
        Wl[r][c4 + 0] = v[0]; Wl[r][c4 + 1] = v[1];
        Wl[r][c4 + 2] = v[2]; Wl[r][c4 + 3] = v[3];
    }
#pragma unroll
    for (int it = 0; it < 4; it++) {           // G: 64x64 fp32
        const int ci = it * 256 + t;
        const int r = ci >> 4, c4 = (ci & 15) * 4;
        *(float4v*)&Gl[r][c4] = *(const float4v*)&Gh[r * 64 + c4];
    }
    __syncthreads();

    const int ty = t >> 4, tx = t & 15;
    float acc[4][4] = {};
    for (int k = 0; k < 64; k++) {
        const float a0 = Wl[4 * ty + 0][k];
        const float a1 = Wl[4 * ty + 1][k];
        const float a2 = Wl[4 * ty + 2][k];
        const float a3 = Wl[4 * ty + 3][k];
        float4v g = *(const float4v*)&Gl[k][4 * tx];
#pragma unroll
        for (int j = 0; j < 4; j++) {
            acc[0][j] += a0 * g[j];
            acc[1][j] += a1 * g[j];
            acc[2][j] += a2 * g[j];
            acc[3][j] += a3 * g[j];
        }
    }
    const float scale = 1.0f / 32.0f;  // 1/sqrt(EMBED)
    __hip_bfloat16* Wt = WeffT + (long)b * EMBED * NPAD;
#pragma unroll
    for (int i = 0; i < 4; i++) {
        const int gr = n0 + 4 * ty + i;
        short4v ov;
#pragma unroll
        for (int j = 0; j < 4; j++)
            ((__hip_bfloat16*)&ov)[j] = __float2bfloat16(acc[i][j] * scale);
        *(short4v*)(Wt + (long)gr * EMBED + h * HDIM + 4 * tx) = ov;
    }
}

// ---------------------------------------------------------------------------
extern "C" void kernel_launch(void* const* d_in, const int* in_sizes, int n_in,
                              void* d_out, int out_size, void* d_ws, size_t ws_size,
                              hipStream_t stream) {
    const float* x     = (const float*)d_in[0];
    const float* W_in  = (const float*)d_in[1];
    const float* b_in  = (const float*)d_in[2];
    const float* W_out = (const float*)d_in[3];
    const float* b_out = (const float*)d_in[4];
    float* out = (float*)d_out;

    char* ws = (char*)d_ws;
    __hip_bfloat16* xb    = (__hip_bfloat16*)(ws);                 // 8 MiB
    __hip_bfloat16* Winb  = (__hip_bfloat16*)(ws + (8u  << 20));   // 2 MiB
    __hip_bfloat16* P     = (__hip_bfloat16*)(ws + (10u << 20));   // 8 MiB
    float*          G     = (float*)(ws + (18u << 20));            // 512 KiB
    __hip_bfloat16* WeffT = (__hip_bfloat16*)(ws + (19u << 20));   // 4 MiB (2 batches)

    // 1) fp32->bf16 converts + G zero
    conv_inputs<<<(XN4 + WN4) / 256, 256, 0, stream>>>(x, W_in, xb, Winb, G);
    // 2) P = x @ W_in^T + b_in   [4096 x 1024] bf16
    gemm_bt_bias<__hip_bfloat16><<<dim3(32, 8), 256, 0, stream>>>(xb, Winb, b_in, P, EMBED, NPAD, NPAD, 0);
    // 3) G[bh] = P_h^T P_h
    gram_kernel<<<dim3(32, 16), 256, 0, stream>>>(P, G);
    // 4) WeffT[b] = scale * (G . Wout^T) per head block
    weff_kernel<<<dim3(16, 16, 2), 256, 0, stream>>>(W_out, G, WeffT);
    // 5) out = P @ WeffT^T + b_out   [4096 x 1000] fp32, batch-strided B
    gemm_bt_bias<float><<<dim3(32, 8), 256, 0, stream>>>(P, WeffT, b_out, out, EMBED, NCLS, NCLS, (long)EMBED * NPAD);
}

// Round 6
// 153.909 us; speedup vs baseline: 1.0459x; 1.0459x over previous
//
#include <hip/hip_runtime.h>
#include <hip/hip_bf16.h>
#include <cstdint>

#define EMBED   1024
#define NHEADS  16
#define HDIM    64
#define SEQ     2048
#define BSZ     2
#define MTOT    (BSZ*SEQ)   // 4096
#define NCLS    1000
#define NPAD    1024

typedef __attribute__((ext_vector_type(8))) short short8;
typedef __attribute__((ext_vector_type(4))) short short4v;
typedef __attribute__((ext_vector_type(4))) float float4v;

typedef __attribute__((address_space(3))) unsigned lds_uint;
typedef __attribute__((address_space(1))) const unsigned gbl_uint;

__device__ __forceinline__ void gl2lds16(const void* g, void* l) {
    __builtin_amdgcn_global_load_lds((gbl_uint*)g, (lds_uint*)l, 16, 0, 0);
}

#define WAITVM6() asm volatile("s_waitcnt vmcnt(6)" ::: "memory")
#define WAITVM0() asm volatile("s_waitcnt vmcnt(0)" ::: "memory")
#define BAR()     asm volatile("s_barrier" ::: "memory")

__device__ __forceinline__ void storeC(float* p, float v) { *p = v; }
__device__ __forceinline__ void storeC(__hip_bfloat16* p, float v) { *p = __float2bfloat16(v); }

// ---------------------------------------------------------------------------
// Convert fp32 x, W_in to bf16 ws copies; zero G. (W_out handled in weff.)
// ---------------------------------------------------------------------------
#define XN4  ((MTOT*EMBED)/4)    // 1,048,576
#define WN4  ((EMBED*EMBED)/4)   // 262,144
#define GN4  (32*64*64/4)        // 32,768
__global__ __launch_bounds__(256)
void conv_inputs(const float* __restrict__ x, const float* __restrict__ Win,
                 __hip_bfloat16* __restrict__ xb, __hip_bfloat16* __restrict__ Winb,
                 float* __restrict__ G) {
    const long i4 = (long)blockIdx.x * 256 + threadIdx.x;  // float4 index
    if (i4 < GN4)
        *(float4v*)(G + i4 * 4) = (float4v){0.f, 0.f, 0.f, 0.f};
    float4v v;
    __hip_bfloat16* dst;
    if (i4 < XN4) {
        v = *(const float4v*)(x + i4 * 4);
        dst = xb + i4 * 4;
    } else {
        const long j = i4 - XN4;
        v = *(const float4v*)(Win + j * 4);
        dst = Winb + j * 4;
    }
    short4v o;
#pragma unroll
    for (int u = 0; u < 4; u++)
        ((__hip_bfloat16*)&o)[u] = __float2bfloat16(v[u]);
    *(short4v*)dst = o;
}

// ---------------------------------------------------------------------------
// GEMM: C[m][n] = sum_k A[m][k]*B[n][k] + bias[n]  (row-major, B^T input)
// 128x64 tile, BK=64, grid 512 blocks = 2 blocks/CU (inter-block overlap
// hides staging latency + barrier drain). XOR-swizzled LDS, double-buffered
// (48 KiB), s_waitcnt vmcnt(6): prefetch stays in flight across barrier.
// ---------------------------------------------------------------------------
template <typename CT>
__global__ __launch_bounds__(256)
void gemm_bt_bias(const __hip_bfloat16* __restrict__ A,
                  const __hip_bfloat16* __restrict__ B,
                  const float* __restrict__ bias,
                  CT* __restrict__ C,
                  int K, int nstore, int cstride, long bstride) {
    __shared__ __hip_bfloat16 As[2][128 * 64];   // 2 x 16 KiB
    __shared__ __hip_bfloat16 Bs[2][64 * 64];    // 2 x  8 KiB

    const int t    = threadIdx.x;
    const int bm   = blockIdx.x * 128;
    const int bn   = blockIdx.y * 64;
    const __hip_bfloat16* Bb = B + (long)(bm >> 11) * bstride;
    const int wave = t >> 6, lane = t & 63;
    const int wm   = (wave & 1) * 64, wn = (wave >> 1) * 32;
    const int lrow = lane & 15, lq = lane >> 4;

    // staging map: chunk ci; LDS slot ci holds global
    // (row = ci>>3, k-chunk = (ci&7)^(row&7))  [16B chunks, 8 per 64-k row]
    const __hip_bfloat16* Arow[4];   // A: 1024 chunks, 4/thread
    const __hip_bfloat16* Brow[2];   // B: 512 chunks, 2/thread
#pragma unroll
    for (int i = 0; i < 4; i++) {
        const int ci = i * 256 + t;
        const int r  = ci >> 3;
        const int sc = ((ci & 7) ^ (r & 7)) * 8;
        Arow[i] = A + (long)(bm + r) * K + sc;
    }
#pragma unroll
    for (int i = 0; i < 2; i++) {
        const int ci = i * 256 + t;
        const int r  = ci >> 3;
        const int sc = ((ci & 7) ^ (r & 7)) * 8;
        Brow[i] = Bb + (long)(bn + r) * K + sc;
    }

    float4v acc[4][2];
#pragma unroll
    for (int i = 0; i < 4; i++)
#pragma unroll
        for (int j = 0; j < 2; j++) acc[i][j] = (float4v){0.f, 0.f, 0.f, 0.f};

    const int nIter = K >> 6;   // 16

#define STAGE_TILE(k0, buf)                                                     \
    do {                                                                        \
        _Pragma("unroll")                                                       \
        for (int i = 0; i < 4; i++)                                             \
            gl2lds16(Arow[i] + (k0), (char*)As[buf] + (i * 256 + t) * 16);      \
        _Pragma("unroll")                                                       \
        for (int i = 0; i < 2; i++)                                             \
            gl2lds16(Brow[i] + (k0), (char*)Bs[buf] + (i * 256 + t) * 16);      \
    } while (0)

    STAGE_TILE(0, 0);

    for (int it = 0; it < nIter; ++it) {
        const int cur = it & 1, nxt = cur ^ 1;
        if (it + 1 < nIter) {
            STAGE_TILE((it + 1) << 6, nxt);
            WAITVM6();   // current tile's 6 loads done; prefetch in flight
        } else {
            WAITVM0();
        }
        BAR();           // tile `cur` staged for all waves

        const __hip_bfloat16* Ac = As[cur];
        const __hip_bfloat16* Bc = Bs[cur];
#pragma unroll
        for (int kk = 0; kk < 2; kk++) {
            short8 af[4], bf[2];
#pragma unroll
            for (int i = 0; i < 4; i++) {
                const int row = wm + i * 16 + lrow;
                const int sc  = (kk * 4 + lq) ^ (row & 7);
                af[i] = *(const short8*)(Ac + row * 64 + sc * 8);
            }
#pragma unroll
            for (int j = 0; j < 2; j++) {
                const int row = wn + j * 16 + lrow;
                const int sc  = (kk * 4 + lq) ^ (row & 7);
                bf[j] = *(const short8*)(Bc + row * 64 + sc * 8);
            }
#pragma unroll
            for (int i = 0; i < 4; i++)
#pragma unroll
                for (int j = 0; j < 2; j++)
                    acc[i][j] = __builtin_amdgcn_mfma_f32_16x16x32_bf16(af[i], bf[j], acc[i][j], 0, 0, 0);
        }
        BAR();           // all waves done reading `cur` before it's overwritten
    }
#undef STAGE_TILE

    // epilogue: C/D layout col=lane&15, row=lq*4+reg
    float bv[2];
#pragma unroll
    for (int j = 0; j < 2; j++) {
        const int gn = bn + wn + j * 16 + lrow;
        bv[j] = (gn < nstore) ? bias[gn] : 0.f;
    }
#pragma unroll
    for (int i = 0; i < 4; i++) {
        const int gm0 = bm + wm + i * 16 + lq * 4;
#pragma unroll
        for (int j = 0; j < 2; j++) {
            const int gn = bn + wn + j * 16 + lrow;
            if (gn < nstore) {
#pragma unroll
                for (int r = 0; r < 4; r++)
                    storeC(&C[(long)(gm0 + r) * cstride + gn], acc[i][j][r] + bv[j]);
            }
        }
    }
}

// ---------------------------------------------------------------------------
// Gram: G[bh][d1][d2] += sum over 128 rows of P[s][d1]*P[s][d2]  (fp32 atomics)
// Pl stride 68: float4 accesses stay 16B-aligned, banks spread (no 16-way).
// ---------------------------------------------------------------------------
__global__ __launch_bounds__(256)
void gram_kernel(const __hip_bfloat16* __restrict__ P, float* __restrict__ G) {
    const int bh = blockIdx.x;       // 0..31
    const int ck = blockIdx.y;       // 0..15
    const int b = bh >> 4, h = bh & 15;
    const int row0 = b * SEQ + ck * 128;

    __shared__ float Pl[128][68];
    const int t = threadIdx.x;
#pragma unroll
    for (int it = 0; it < 4; it++) {
        const int ci = it * 256 + t;
        const int r = ci >> 3, c8 = (ci & 7) * 8;
        short8 v = *(const short8*)(P + (long)(row0 + r) * EMBED + h * HDIM + c8);
        float4v f0, f1;
#pragma unroll
        for (int u = 0; u < 4; u++) {
            f0[u] = __bfloat162float(((const __hip_bfloat16*)&v)[u]);
            f1[u] = __bfloat162float(((const __hip_bfloat16*)&v)[u + 4]);
        }
        *(float4v*)&Pl[r][c8]     = f0;
        *(float4v*)&Pl[r][c8 + 4] = f1;
    }
    __syncthreads();

    const int ty = t >> 4, tx = t & 15;
    float acc[4][4] = {};
    for (int k = 0; k < 128; k++) {
        float4v a  = *(const float4v*)&Pl[k][4 * ty];
        float4v bb = *(const float4v*)&Pl[k][4 * tx];
#pragma unroll
        for (int i = 0; i < 4; i++)
#pragma unroll
            for (int j = 0; j < 4; j++) acc[i][j] += a[i] * bb[j];
    }
    float* Gh = G + bh * 4096;
#pragma unroll
    for (int i = 0; i < 4; i++)
#pragma unroll
        for (int j = 0; j < 4; j++)
            atomicAdd(&Gh[(4 * ty + i) * 64 + 4 * tx + j], acc[i][j]);
}

// ---------------------------------------------------------------------------
// Weff: WeffT[b][n][64h+d1] = scale * sum_d Wout[n][64h+d] * G[b,h][d][d1]
// (G symmetric). Reads W_out fp32 directly (rows >= NCLS zeroed).
// ---------------------------------------------------------------------------
__global__ __launch_bounds__(256)
void weff_kernel(const float* __restrict__ Wout, const float* __restrict__ G,
                 __hip_bfloat16* __restrict__ WeffT) {
    const int n0 = blockIdx.x * 64;
    const int h  = blockIdx.y;
    const int b  = blockIdx.z;
    const float* Gh = G + (b * 16 + h) * 4096;

    __shared__ float Wl[64][65];
    __shared__ float Gl[64][64];
    const int t = threadIdx.x;

#pragma unroll
    for (int it = 0; it < 4; it++) {           // Wout slice 64x64 fp32
        const int ci = it * 256 + t;
        const int r = ci >> 4, c4 = (ci & 15) * 4;
        const int gr = n0 + r;
        float4v v = (float4v){0.f, 0.f, 0.f, 0.f};
        if (gr < NCLS)
            v = *(const float4v*)(Wout + (long)gr * EMBED + h * HDIM + c4);
        Wl[r][c4 + 0] = v[0]; Wl[r][c4 + 1] = v[1];
        Wl[r][c4 + 2] = v[2]; Wl[r][c4 + 3] = v[3];
    }
#pragma unroll
    for (int it = 0; it < 4; it++) {           // G: 64x64 fp32
        const int ci = it * 256 + t;
        const int r = ci >> 4, c4 = (ci & 15) * 4;
        *(float4v*)&Gl[r][c4] = *(const float4v*)&Gh[r * 64 + c4];
    }
    __syncthreads();

    const int ty = t >> 4, tx = t & 15;
    float acc[4][4] = {};
    for (int k = 0; k < 64; k++) {
        const float a0 = Wl[4 * ty + 0][k];
        const float a1 = Wl[4 * ty + 1][k];
        const float a2 = Wl[4 * ty + 2][k];
        const float a3 = Wl[4 * ty + 3][k];
        float4v g = *(const float4v*)&Gl[k][4 * tx];
#pragma unroll
        for (int j = 0; j < 4; j++) {
            acc[0][j] += a0 * g[j];
            acc[1][j] += a1 * g[j];
            acc[2][j] += a2 * g[j];
            acc[3][j] += a3 * g[j];
        }
    }
    const float scale = 1.0f / 32.0f;  // 1/sqrt(EMBED)
    __hip_bfloat16* Wt = WeffT + (long)b * EMBED * NPAD;
#pragma unroll
    for (int i = 0; i < 4; i++) {
        const int gr = n0 + 4 * ty + i;
        short4v ov;
#pragma unroll
        for (int j = 0; j < 4; j++)
            ((__hip_bfloat16*)&ov)[j] = __float2bfloat16(acc[i][j] * scale);
        *(short4v*)(Wt + (long)gr * EMBED + h * HDIM + 4 * tx) = ov;
    }
}

// ---------------------------------------------------------------------------
extern "C" void kernel_launch(void* const* d_in, const int* in_sizes, int n_in,
                              void* d_out, int out_size, void* d_ws, size_t ws_size,
                              hipStream_t stream) {
    const float* x     = (const float*)d_in[0];
    const float* W_in  = (const float*)d_in[1];
    const float* b_in  = (const float*)d_in[2];
    const float* W_out = (const float*)d_in[3];
    const float* b_out = (const float*)d_in[4];
    float* out = (float*)d_out;

    char* ws = (char*)d_ws;
    __hip_bfloat16* xb    = (__hip_bfloat16*)(ws);                 // 8 MiB
    __hip_bfloat16* Winb  = (__hip_bfloat16*)(ws + (8u  << 20));   // 2 MiB
    __hip_bfloat16* P     = (__hip_bfloat16*)(ws + (10u << 20));   // 8 MiB
    float*          G     = (float*)(ws + (18u << 20));            // 512 KiB
    __hip_bfloat16* WeffT = (__hip_bfloat16*)(ws + (19u << 20));   // 4 MiB (2 batches)

    // 1) fp32->bf16 converts + G zero
    conv_inputs<<<(XN4 + WN4) / 256, 256, 0, stream>>>(x, W_in, xb, Winb, G);
    // 2) P = x @ W_in^T + b_in   [4096 x 1024] bf16   (512 blocks, 2/CU)
    gemm_bt_bias<__hip_bfloat16><<<dim3(32, 16), 256, 0, stream>>>(xb, Winb, b_in, P, EMBED, NPAD, NPAD, 0);
    // 3) G[bh] = P_h^T P_h
    gram_kernel<<<dim3(32, 16), 256, 0, stream>>>(P, G);
    // 4) WeffT[b] = scale * (G . Wout^T) per head block
    weff_kernel<<<dim3(16, 16, 2), 256, 0, stream>>>(W_out, G, WeffT);
    // 5) out = P @ WeffT^T + b_out   [4096 x 1000] fp32  (512 blocks, 2/CU)
    gemm_bt_bias<float><<<dim3(32, 16), 256, 0, stream>>>(P, WeffT, b_out, out, EMBED, NCLS, NCLS, (long)EMBED * NPAD);
}

// Round 7
// 152.208 us; speedup vs baseline: 1.0576x; 1.0112x over previous
//
#include <hip/hip_runtime.h>
#include <hip/hip_bf16.h>
#include <cstdint>

#define EMBED   1024
#define NHEADS  16
#define HDIM    64
#define SEQ     2048
#define BSZ     2
#define MTOT    (BSZ*SEQ)   // 4096
#define NCLS    1000
#define NPAD    1024

typedef __attribute__((ext_vector_type(8))) short short8;
typedef __attribute__((ext_vector_type(4))) short short4v;
typedef __attribute__((ext_vector_type(4))) float float4v;

typedef __attribute__((address_space(3))) unsigned lds_uint;
typedef __attribute__((address_space(1))) const unsigned gbl_uint;

__device__ __forceinline__ void gl2lds16(const void* g, void* l) {
    __builtin_amdgcn_global_load_lds((gbl_uint*)g, (lds_uint*)l, 16, 0, 0);
}

#define WAITVM6() asm volatile("s_waitcnt vmcnt(6)" ::: "memory")
#define WAITVM0() asm volatile("s_waitcnt vmcnt(0)" ::: "memory")
#define BAR()     asm volatile("s_barrier" ::: "memory")

__device__ __forceinline__ void storeC(float* p, float v) { *p = v; }
__device__ __forceinline__ void storeC(__hip_bfloat16* p, float v) { *p = __float2bfloat16(v); }

// ---------------------------------------------------------------------------
// Convert fp32 x, W_in to bf16 ws copies; zero G. (W_out handled in weff.)
// ---------------------------------------------------------------------------
#define XN4  ((MTOT*EMBED)/4)    // 1,048,576
#define WN4  ((EMBED*EMBED)/4)   // 262,144
#define GN4  (32*64*64/4)        // 32,768
__global__ __launch_bounds__(256)
void conv_inputs(const float* __restrict__ x, const float* __restrict__ Win,
                 __hip_bfloat16* __restrict__ xb, __hip_bfloat16* __restrict__ Winb,
                 float* __restrict__ G) {
    const long i4 = (long)blockIdx.x * 256 + threadIdx.x;  // float4 index
    if (i4 < GN4)
        *(float4v*)(G + i4 * 4) = (float4v){0.f, 0.f, 0.f, 0.f};
    float4v v;
    __hip_bfloat16* dst;
    if (i4 < XN4) {
        v = *(const float4v*)(x + i4 * 4);
        dst = xb + i4 * 4;
    } else {
        const long j = i4 - XN4;
        v = *(const float4v*)(Win + j * 4);
        dst = Winb + j * 4;
    }
    short4v o;
#pragma unroll
    for (int u = 0; u < 4; u++)
        ((__hip_bfloat16*)&o)[u] = __float2bfloat16(v[u]);
    *(short4v*)dst = o;
}

// ---------------------------------------------------------------------------
// GEMM: C[m][n] = sum_k A[m][k]*B[n][k] + bias[n]  (row-major, B^T input)
// 128x64 tile, BK=64, flat 512-block grid with XCD-AWARE SWIZZLE:
//   xcd = blk&7 (round-robin placement), j = blk>>3,
//   bmi = xcd*4 + (j&3)  -> each XCD owns 4 A-tiles (1 MB) x all B (2 MB)
//   => 3 MB working set fits its 4 MiB L2; re-reads stop spilling to L3.
// XOR-swizzled LDS, double-buffered (48 KiB, 2 blocks/CU), vmcnt(6).
// ---------------------------------------------------------------------------
template <typename CT>
__global__ __launch_bounds__(256)
void gemm_bt_bias(const __hip_bfloat16* __restrict__ A,
                  const __hip_bfloat16* __restrict__ B,
                  const float* __restrict__ bias,
                  CT* __restrict__ C,
                  int K, int nstore, int cstride, long bstride) {
    __shared__ __hip_bfloat16 As[2][128 * 64];   // 2 x 16 KiB
    __shared__ __hip_bfloat16 Bs[2][64 * 64];    // 2 x  8 KiB

    const int t    = threadIdx.x;
    const int blk  = blockIdx.x;            // 0..511
    const int xcd  = blk & 7;
    const int j    = blk >> 3;              // 0..63
    const int bm   = (xcd * 4 + (j & 3)) * 128;
    const int bn   = (j >> 2) * 64;
    const __hip_bfloat16* Bb = B + (long)(bm >> 11) * bstride;
    const int wave = t >> 6, lane = t & 63;
    const int wm   = (wave & 1) * 64, wn = (wave >> 1) * 32;
    const int lrow = lane & 15, lq = lane >> 4;

    // staging map: chunk ci; LDS slot ci holds global
    // (row = ci>>3, k-chunk = (ci&7)^(row&7))  [16B chunks, 8 per 64-k row]
    const __hip_bfloat16* Arow[4];   // A: 1024 chunks, 4/thread
    const __hip_bfloat16* Brow[2];   // B: 512 chunks, 2/thread
#pragma unroll
    for (int i = 0; i < 4; i++) {
        const int ci = i * 256 + t;
        const int r  = ci >> 3;
        const int sc = ((ci & 7) ^ (r & 7)) * 8;
        Arow[i] = A + (long)(bm + r) * K + sc;
    }
#pragma unroll
    for (int i = 0; i < 2; i++) {
        const int ci = i * 256 + t;
        const int r  = ci >> 3;
        const int sc = ((ci & 7) ^ (r & 7)) * 8;
        Brow[i] = Bb + (long)(bn + r) * K + sc;
    }

    float4v acc[4][2];
#pragma unroll
    for (int i = 0; i < 4; i++)
#pragma unroll
        for (int jj = 0; jj < 2; jj++) acc[i][jj] = (float4v){0.f, 0.f, 0.f, 0.f};

    const int nIter = K >> 6;   // 16

#define STAGE_TILE(k0, buf)                                                     \
    do {                                                                        \
        _Pragma("unroll")                                                       \
        for (int i = 0; i < 4; i++)                                             \
            gl2lds16(Arow[i] + (k0), (char*)As[buf] + (i * 256 + t) * 16);      \
        _Pragma("unroll")                                                       \
        for (int i = 0; i < 2; i++)                                             \
            gl2lds16(Brow[i] + (k0), (char*)Bs[buf] + (i * 256 + t) * 16);      \
    } while (0)

    STAGE_TILE(0, 0);

    for (int it = 0; it < nIter; ++it) {
        const int cur = it & 1, nxt = cur ^ 1;
        if (it + 1 < nIter) {
            STAGE_TILE((it + 1) << 6, nxt);
            WAITVM6();   // current tile's 6 loads done; prefetch in flight
        } else {
            WAITVM0();
        }
        BAR();           // tile `cur` staged for all waves

        const __hip_bfloat16* Ac = As[cur];
        const __hip_bfloat16* Bc = Bs[cur];
#pragma unroll
        for (int kk = 0; kk < 2; kk++) {
            short8 af[4], bf[2];
#pragma unroll
            for (int i = 0; i < 4; i++) {
                const int row = wm + i * 16 + lrow;
                const int sc  = (kk * 4 + lq) ^ (row & 7);
                af[i] = *(const short8*)(Ac + row * 64 + sc * 8);
            }
#pragma unroll
            for (int jj = 0; jj < 2; jj++) {
                const int row = wn + jj * 16 + lrow;
                const int sc  = (kk * 4 + lq) ^ (row & 7);
                bf[jj] = *(const short8*)(Bc + row * 64 + sc * 8);
            }
#pragma unroll
            for (int i = 0; i < 4; i++)
#pragma unroll
                for (int jj = 0; jj < 2; jj++)
                    acc[i][jj] = __builtin_amdgcn_mfma_f32_16x16x32_bf16(af[i], bf[jj], acc[i][jj], 0, 0, 0);
        }
        BAR();           // all waves done reading `cur` before it's overwritten
    }
#undef STAGE_TILE

    // epilogue: C/D layout col=lane&15, row=lq*4+reg
    float bv[2];
#pragma unroll
    for (int jj = 0; jj < 2; jj++) {
        const int gn = bn + wn + jj * 16 + lrow;
        bv[jj] = (gn < nstore) ? bias[gn] : 0.f;
    }
#pragma unroll
    for (int i = 0; i < 4; i++) {
        const int gm0 = bm + wm + i * 16 + lq * 4;
#pragma unroll
        for (int jj = 0; jj < 2; jj++) {
            const int gn = bn + wn + jj * 16 + lrow;
            if (gn < nstore) {
#pragma unroll
                for (int r = 0; r < 4; r++)
                    storeC(&C[(long)(gm0 + r) * cstride + gn], acc[i][jj][r] + bv[jj]);
            }
        }
    }
}

// ---------------------------------------------------------------------------
// Gram: G[bh][d1][d2] += sum over 128 rows of P[s][d1]*P[s][d2]  (fp32 atomics)
// Pl stride 68: float4 accesses stay 16B-aligned, banks spread (no 16-way).
// ---------------------------------------------------------------------------
__global__ __launch_bounds__(256)
void gram_kernel(const __hip_bfloat16* __restrict__ P, float* __restrict__ G) {
    const int bh = blockIdx.x;       // 0..31
    const int ck = blockIdx.y;       // 0..15
    const int b = bh >> 4, h = bh & 15;
    const int row0 = b * SEQ + ck * 128;

    __shared__ float Pl[128][68];
    const int t = threadIdx.x;
#pragma unroll
    for (int it = 0; it < 4; it++) {
        const int ci = it * 256 + t;
        const int r = ci >> 3, c8 = (ci & 7) * 8;
        short8 v = *(const short8*)(P + (long)(row0 + r) * EMBED + h * HDIM + c8);
        float4v f0, f1;
#pragma unroll
        for (int u = 0; u < 4; u++) {
            f0[u] = __bfloat162float(((const __hip_bfloat16*)&v)[u]);
            f1[u] = __bfloat162float(((const __hip_bfloat16*)&v)[u + 4]);
        }
        *(float4v*)&Pl[r][c8]     = f0;
        *(float4v*)&Pl[r][c8 + 4] = f1;
    }
    __syncthreads();

    const int ty = t >> 4, tx = t & 15;
    float acc[4][4] = {};
    for (int k = 0; k < 128; k++) {
        float4v a  = *(const float4v*)&Pl[k][4 * ty];
        float4v bb = *(const float4v*)&Pl[k][4 * tx];
#pragma unroll
        for (int i = 0; i < 4; i++)
#pragma unroll
            for (int j = 0; j < 4; j++) acc[i][j] += a[i] * bb[j];
    }
    float* Gh = G + bh * 4096;
#pragma unroll
    for (int i = 0; i < 4; i++)
#pragma unroll
        for (int j = 0; j < 4; j++)
            atomicAdd(&Gh[(4 * ty + i) * 64 + 4 * tx + j], acc[i][j]);
}

// ---------------------------------------------------------------------------
// Weff: WeffT[b][n][64h+d1] = scale * sum_d Wout[n][64h+d] * G[b,h][d][d1]
// (G symmetric). Reads W_out fp32 directly (rows >= NCLS zeroed).
// ---------------------------------------------------------------------------
__global__ __launch_bounds__(256)
void weff_kernel(const float* __restrict__ Wout, const float* __restrict__ G,
                 __hip_bfloat16* __restrict__ WeffT) {
    const int n0 = blockIdx.x * 64;
    const int h  = blockIdx.y;
    const int b  = blockIdx.z;
    const float* Gh = G + (b * 16 + h) * 4096;

    __shared__ float Wl[64][65];
    __shared__ float Gl[64][64];
    const int t = threadIdx.x;

#pragma unroll
    for (int it = 0; it < 4; it++) {           // Wout slice 64x64 fp32
        const int ci = it * 256 + t;
        const int r = ci >> 4, c4 = (ci & 15) * 4;
        const int gr = n0 + r;
        float4v v = (float4v){0.f, 0.f, 0.f, 0.f};
        if (gr < NCLS)
            v = *(const float4v*)(Wout + (long)gr * EMBED + h * HDIM + c4);
        Wl[r][c4 + 0] = v[0]; Wl[r][c4 + 1] = v[1];
        Wl[r][c4 + 2] = v[2]; Wl[r][c4 + 3] = v[3];
    }
#pragma unroll
    for (int it = 0; it < 4; it++) {           // G: 64x64 fp32
        const int ci = it * 256 + t;
        const int r = ci >> 4, c4 = (ci & 15) * 4;
        *(float4v*)&Gl[r][c4] = *(const float4v*)&Gh[r * 64 + c4];
    }
    __syncthreads();

    const int ty = t >> 4, tx = t & 15;
    float acc[4][4] = {};
    for (int k = 0; k < 64; k++) {
        const float a0 = Wl[4 * ty + 0][k];
        const float a1 = Wl[4 * ty + 1][k];
        const float a2 = Wl[4 * ty + 2][k];
        const float a3 = Wl[4 * ty + 3][k];
        float4v g = *(const float4v*)&Gl[k][4 * tx];
#pragma unroll
        for (int j = 0; j < 4; j++) {
            acc[0][j] += a0 * g[j];
            acc[1][j] += a1 * g[j];
            acc[2][j] += a2 * g[j];
            acc[3][j] += a3 * g[j];
        }
    }
    const float scale = 1.0f / 32.0f;  // 1/sqrt(EMBED)
    __hip_bfloat16* Wt = WeffT + (long)b * EMBED * NPAD;
#pragma unroll
    for (int i = 0; i < 4; i++) {
        const int gr = n0 + 4 * ty + i;
        short4v ov;
#pragma unroll
        for (int j = 0; j < 4; j++)
            ((__hip_bfloat16*)&ov)[j] = __float2bfloat16(acc[i][j] * scale);
        *(short4v*)(Wt + (long)gr * EMBED + h * HDIM + 4 * tx) = ov;
    }
}

// ---------------------------------------------------------------------------
extern "C" void kernel_launch(void* const* d_in, const int* in_sizes, int n_in,
                              void* d_out, int out_size, void* d_ws, size_t ws_size,
                              hipStream_t stream) {
    const float* x     = (const float*)d_in[0];
    const float* W_in  = (const float*)d_in[1];
    const float* b_in  = (const float*)d_in[2];
    const float* W_out = (const float*)d_in[3];
    const float* b_out = (const float*)d_in[4];
    float* out = (float*)d_out;

    char* ws = (char*)d_ws;
    __hip_bfloat16* xb    = (__hip_bfloat16*)(ws);                 // 8 MiB
    __hip_bfloat16* Winb  = (__hip_bfloat16*)(ws + (8u  << 20));   // 2 MiB
    __hip_bfloat16* P     = (__hip_bfloat16*)(ws + (10u << 20));   // 8 MiB
    float*          G     = (float*)(ws + (18u << 20));            // 512 KiB
    __hip_bfloat16* WeffT = (__hip_bfloat16*)(ws + (19u << 20));   // 4 MiB (2 batches)

    // 1) fp32->bf16 converts + G zero
    conv_inputs<<<(XN4 + WN4) / 256, 256, 0, stream>>>(x, W_in, xb, Winb, G);
    // 2) P = x @ W_in^T + b_in   [4096 x 1024] bf16   (512 blocks, XCD-swizzled)
    gemm_bt_bias<__hip_bfloat16><<<512, 256, 0, stream>>>(xb, Winb, b_in, P, EMBED, NPAD, NPAD, 0);
    // 3) G[bh] = P_h^T P_h
    gram_kernel<<<dim3(32, 16), 256, 0, stream>>>(P, G);
    // 4) WeffT[b] = scale * (G . Wout^T) per head block
    weff_kernel<<<dim3(16, 16, 2), 256, 0, stream>>>(W_out, G, WeffT);
    // 5) out = P @ WeffT^T + b_out   [4096 x 1000] fp32 (512 blocks, XCD-swizzled)
    gemm_bt_bias<float><<<512, 256, 0, stream>>>(P, WeffT, b_out, out, EMBED, NCLS, NCLS, (long)EMBED * NPAD);
}